// Round 4
// baseline (1640.209 us; speedup 1.0000x reference)
//
#include <hip/hip_runtime.h>
#include <hip/hip_bf16.h>

// OCRHead: B=4, CIN=720, H=W=128, MID=512, KC=VC=256, NC=19.
// Inputs/outputs: float32. d_out = logits[1245184] ++ aux_logits[1245184] (f32)
//
// Conv3x3 as MFMA implicit GEMM, 2-ROW blocks: each block computes 128 oc x
// 256 px (two adjacent h rows) so staging (4 feats rows vs 6), barriers and
// A-fragment loads amortize over 2x the MFMA work. Reg-staged 1-row version
// measured 635 TF = the m151 reg-staged 2-barrier ceiling; this cuts per-output
// overhead ~33-50%.
//
// LDS tile [rr 4][w' 130][ci 40] bf16 (41.6 KB), halo cols w'=0,129 zeroed.
//   write: 2x ds_write_b128/lane/row; lane word-stride 40==8 mod 32 ->
//          16 lanes per 4-bank window = 2-way conflict (free, m136).
//   read:  b128 frags at stride 20 words -> 8 words/bank = wave minimum.
// Staging loads: wave w owns ci slice w*8..+7, lane owns col pair -> each
// load instruction is one fully-contiguous 512B row.
//
// Grid swizzle: 1024 blocks; bid=((gp*4+oc_t)*8+xcd): 4 oc_t sharers of a
// row-pair land adjacent on one XCD (FETCH dropped 2.9x when introduced).
//
// d_ws: X bf16 only. Apack + small f32 scratch live inside d_out:
//   Apack at d_out[0..6.78MB)  (consumed by conv; logits half overwritten later)
//   small scratch at tail of aux half (overwritten by aux_final, which runs last)

__device__ __forceinline__ float u_lo(unsigned u) { return __uint_as_float(u << 16); }
__device__ __forceinline__ float u_hi(unsigned u) { return __uint_as_float(u & 0xffff0000u); }
__device__ __forceinline__ float scrub(float v) { return isfinite(v) ? v : 1e4f; }
#define BF2F(h) __bfloat162float(h)

typedef __attribute__((ext_vector_type(8))) short bf16x8;
typedef __attribute__((ext_vector_type(4))) float f32x4;

// ---- d_out scratch offsets (bytes). d_out total = 9,961,472 B ----
#define SO_APACK  0ull            // 9*512*736*2 = 6,782,976
#define TAIL0     9371648ull      // = 9,961,472 - 589,824
#define TA_AUXWT  (TAIL0 + 0ull)       // 38,912
#define TA_CLSWT  (TAIL0 + 38912ull)   // 38,912
#define TA_SS     (TAIL0 + 77824ull)   // 4,096
#define TA_PSUM   (TAIL0 + 81920ull)   // 512    (memset 0)
#define TA_CTX    (TAIL0 + 82432ull)   // 155,648 (memset 0)
#define TA_KMAT   (TAIL0 + 238080ull)  // 77,824
#define TA_VMAT   (TAIL0 + 315904ull)  // 77,824
#define TA_FCLS   (TAIL0 + 393728ull)  // 19,456
#define TA_MT     (TAIL0 + 413184ull)  // 155,648
#define TA_G      (TAIL0 + 568832ull)  // 5,776  ; end 574,608 < 589,824

// LDS B-tile geometry (elements): [rr 4][w' 130][ci 40]
#define LDS_CI   40              // padded ci stride (16B-aligned frag reads)
#define LDS_WP   (130 * LDS_CI)  // 5200 per rr plane
#define LDS_TOT  (4 * LDS_WP)    // 20,800 elements = 41,600 B

// ---- K0: transpose 19x512 weights to [512][19] f32 ----
__global__ __launch_bounds__(256) void prep_small_kernel(
    const float* __restrict__ aux_w, const float* __restrict__ cls_w,
    float* __restrict__ aux_wt, float* __restrict__ cls_wt) {
  int i = blockIdx.x * 256 + threadIdx.x;
  if (i < 9728) {
    int k = i >> 9, c = i & 511;
    aux_wt[c * 19 + k] = aux_w[i];
    cls_wt[c * 19 + k] = cls_w[i];
  }
}

// ---- K0b: pack conv weights f32 [512][720][3][3] -> bf16 Apack[9][512][736] ----
__global__ __launch_bounds__(256) void prep_apack_kernel(
    const float* __restrict__ w3, __hip_bfloat16* __restrict__ Apack) {
  int idx = blockIdx.x * 256 + threadIdx.x;
  if (idx >= 512 * 736) return;
  int oc = idx / 736, ci = idx - (idx / 736) * 736;
  float v[9];
#pragma unroll
  for (int k = 0; k < 9; ++k) v[k] = 0.f;
  if (ci < 720) {
    const float* src = w3 + ((size_t)oc * 720 + ci) * 9;
#pragma unroll
    for (int k = 0; k < 9; ++k) v[k] = src[k];
  }
#pragma unroll
  for (int k = 0; k < 9; ++k)
    Apack[((size_t)k * 512 + oc) * 736 + ci] = __float2bfloat16(v[k]);
}

// ---- K1: conv3x3 via MFMA implicit GEMM. Block: 128 oc x 256 px (2 rows) ----
__global__ __launch_bounds__(256) void conv_mfma_kernel(
    const float* __restrict__ feats, const __hip_bfloat16* __restrict__ Apack,
    __hip_bfloat16* __restrict__ X) {
  __shared__ short Blds[LDS_TOT];
  // bid = ((gp*4 + oc_t)*8 + xcd); gx2 = gp*8 + xcd in 0..255 = b*64 + h'
  int bid = blockIdx.x;
  int xcd = bid & 7;
  int slot = bid >> 3;              // 0..127
  int oc_t = slot & 3;              // 0..3
  int gx2 = (slot >> 2) * 8 + xcd;  // 0..255
  int b = gx2 >> 6, h0 = (gx2 & 63) * 2;
  int tid = threadIdx.x;
  int wave = tid >> 6, lane = tid & 63;
  int wm = wave >> 1, wn = wave & 1; // wm: oc half, wn: output row
  int l15 = lane & 15, quad = lane >> 4;

  f32x4 acc[4][8];
#pragma unroll
  for (int mb = 0; mb < 4; ++mb)
#pragma unroll
    for (int nb = 0; nb < 8; ++nb) acc[mb][nb] = (f32x4){0.f, 0.f, 0.f, 0.f};

  // zero halo columns w'=0 and w'=129 for all 4 rr planes
  for (int i = tid; i < 320; i += 256) {
    int rr = i / 80, rem = i - rr * 80;
    int wp = (rem < 40) ? 0 : 129;
    int ci = (rem < 40) ? rem : rem - 40;
    Blds[rr * LDS_WP + wp * LDS_CI + ci] = 0;
  }

  const short* Ab = (const short*)Apack;
  int oc_row = oc_t * 128 + wm * 64 + l15;

  for (int cb = 0; cb < 23; ++cb) {
    __syncthreads();  // previous iteration's reads done before overwrite
    // ---- stage 32 ci x 4 rows x 128 cols into LDS (transposed, bf16) ----
    // wave owns ci = cb*32 + wave*8 .. +7 (720%8==0 -> wave-uniform predicate);
    // lane owns cols lane*2, lane*2+1. Rows rr=0..3 = h0-1 .. h0+2.
    int ci0 = cb * 32 + wave * 8;
    bool civ = (ci0 < 720);
    const float* fb = feats + (((size_t)b * 720 + ci0) << 14) + lane * 2;
#pragma unroll
    for (int rr = 0; rr < 4; ++rr) {
      int hr = h0 - 1 + rr;
      float2 v0 = {0.f, 0.f}, v1 = v0, v2 = v0, v3 = v0,
             v4 = v0, v5 = v0, v6 = v0, v7 = v0;
      if (civ && ((unsigned)hr < 128u)) {
        const float* p = fb + hr * 128;
        v0 = *reinterpret_cast<const float2*>(p);
        v1 = *reinterpret_cast<const float2*>(p + 16384);
        v2 = *reinterpret_cast<const float2*>(p + 32768);
        v3 = *reinterpret_cast<const float2*>(p + 49152);
        v4 = *reinterpret_cast<const float2*>(p + 65536);
        v5 = *reinterpret_cast<const float2*>(p + 81920);
        v6 = *reinterpret_cast<const float2*>(p + 98304);
        v7 = *reinterpret_cast<const float2*>(p + 114688);
      }
      union { bf16x8 v; __hip_bfloat16 h[8]; } E, O;
      E.h[0] = __float2bfloat16(v0.x); O.h[0] = __float2bfloat16(v0.y);
      E.h[1] = __float2bfloat16(v1.x); O.h[1] = __float2bfloat16(v1.y);
      E.h[2] = __float2bfloat16(v2.x); O.h[2] = __float2bfloat16(v2.y);
      E.h[3] = __float2bfloat16(v3.x); O.h[3] = __float2bfloat16(v3.y);
      E.h[4] = __float2bfloat16(v4.x); O.h[4] = __float2bfloat16(v4.y);
      E.h[5] = __float2bfloat16(v5.x); O.h[5] = __float2bfloat16(v5.y);
      E.h[6] = __float2bfloat16(v6.x); O.h[6] = __float2bfloat16(v6.y);
      E.h[7] = __float2bfloat16(v7.x); O.h[7] = __float2bfloat16(v7.y);
      short* wb = &Blds[rr * LDS_WP + (lane * 2 + 1) * LDS_CI + wave * 8];
      *reinterpret_cast<bf16x8*>(wb) = E.v;
      *reinterpret_cast<bf16x8*>(wb + LDS_CI) = O.v;
    }
    __syncthreads();
    // ---- 9 shift-GEMM K-steps (K=32 each), both rows ----
#pragma unroll
    for (int r = 0; r < 3; ++r) {
#pragma unroll
      for (int dw = 0; dw < 3; ++dw) {
        int plane = r * 3 + dw;
        const short* ap = Ab + ((size_t)plane * 512 + oc_row) * 736 + cb * 32 + quad * 8;
        bf16x8 af[4];
#pragma unroll
        for (int mb = 0; mb < 4; ++mb)
          af[mb] = *(const bf16x8*)(ap + (size_t)mb * 16 * 736);
        const short* bbase = &Blds[(wn + r) * LDS_WP + dw * LDS_CI + quad * 8];
#pragma unroll
        for (int nb = 0; nb < 8; ++nb) {
          int w = nb * 16 + l15;
          bf16x8 bfr = *(const bf16x8*)(bbase + w * LDS_CI);
#pragma unroll
          for (int mb = 0; mb < 4; ++mb)
            acc[mb][nb] = __builtin_amdgcn_mfma_f32_16x16x32_bf16(
                af[mb], bfr, acc[mb][nb], 0, 0, 0);
        }
      }
    }
  }
  // ---- epilogue: row h0+wn, col nb*16+l15; oc row = quad*4+reg in 16-block ----
  int h = h0 + wn;
#pragma unroll
  for (int mb = 0; mb < 4; ++mb)
#pragma unroll
    for (int nb = 0; nb < 8; ++nb) {
      int w = nb * 16 + l15;
#pragma unroll
      for (int reg = 0; reg < 4; ++reg) {
        int oc = oc_t * 128 + wm * 64 + mb * 16 + quad * 4 + reg;
        X[(((size_t)b * 512 + oc) << 14) + h * 128 + w] =
            __float2bfloat16(acc[mb][nb][reg]);
      }
    }
}

// ---- K2: per-channel BN stats -> scale/shift ----
__global__ __launch_bounds__(256) void bn_stats_kernel(
    const __hip_bfloat16* __restrict__ X, const float* __restrict__ gamma,
    const float* __restrict__ beta, float* __restrict__ ss_out) {
  int c = blockIdx.x, tid = threadIdx.x;
  float s = 0.f, ss = 0.f;
  for (int b = 0; b < 4; ++b) {
    const __hip_bfloat16* p = X + (((size_t)b * 512 + c) << 14);
    for (int n = tid * 8; n < 16384; n += 2048) {
      uint4 u = *reinterpret_cast<const uint4*>(p + n);
      unsigned arr[4] = {u.x, u.y, u.z, u.w};
#pragma unroll
      for (int j = 0; j < 4; ++j) {
        float f0 = u_lo(arr[j]), f1 = u_hi(arr[j]);
        s += f0 + f1;
        ss += f0 * f0 + f1 * f1;
      }
    }
  }
#pragma unroll
  for (int off = 32; off > 0; off >>= 1) {
    s += __shfl_down(s, off);
    ss += __shfl_down(ss, off);
  }
  __shared__ float red[8];
  int wid = tid >> 6, lane = tid & 63;
  if (lane == 0) { red[wid] = s; red[4 + wid] = ss; }
  __syncthreads();
  if (tid == 0) {
    s = red[0] + red[1] + red[2] + red[3];
    ss = red[4] + red[5] + red[6] + red[7];
    float mean = s * (1.f / 65536.f);
    float var = ss * (1.f / 65536.f) - mean * mean;
    float gi = gamma[c] * rsqrtf(var + 1e-5f);
    ss_out[c * 2] = gi;
    ss_out[c * 2 + 1] = beta[c] - mean * gi;
  }
}

// ---- K3: x = relu(y*scale+shift) in place (bf16) ----
__global__ __launch_bounds__(256) void bn_apply_kernel(
    __hip_bfloat16* __restrict__ X, const float* __restrict__ ss) {
  size_t idx = ((size_t)blockIdx.x * 256 + threadIdx.x) * 8;
  int c = (int)((idx >> 14) & 511);
  float sc = ss[c * 2], sh = ss[c * 2 + 1];
  uint4 u = *reinterpret_cast<const uint4*>(X + idx);
  unsigned arr[4] = {u.x, u.y, u.z, u.w};
  union { uint4 u; __hip_bfloat16 h[8]; } O;
#pragma unroll
  for (int j = 0; j < 4; ++j) {
    float f0 = fmaxf(fmaf(u_lo(arr[j]), sc, sh), 0.f);
    float f1 = fmaxf(fmaf(u_hi(arr[j]), sc, sh), 0.f);
    O.h[2 * j] = __float2bfloat16(f0);
    O.h[2 * j + 1] = __float2bfloat16(f1);
  }
  *reinterpret_cast<uint4*>(X + idx) = O.u;
}

// ---- K4: aux logits (regs) -> softmax -> ctx/psum accumulation ----
__global__ __launch_bounds__(256) void aux_ctx_kernel(
    const __hip_bfloat16* __restrict__ X, const float* __restrict__ aux_wt,
    const float* __restrict__ aux_b,
    float* __restrict__ ctx, float* __restrict__ psum) {
  int b = blockIdx.y;
  int n0 = blockIdx.x * 256;
  int tid = threadIdx.x;
  __shared__ float pl[19][256];

  const __hip_bfloat16* Xb = X + (((size_t)b * 512) << 14);

  int p0 = n0 + tid;
  float a0[19];
#pragma unroll
  for (int k = 0; k < 19; ++k) a0[k] = aux_b[k];
  for (int c = 0; c < 512; ++c) {
    float f0 = BF2F(Xb[((size_t)c << 14) + p0]);
    const float* wr = aux_wt + c * 19;
#pragma unroll
    for (int k = 0; k < 19; ++k) a0[k] = fmaf(wr[k], f0, a0[k]);
  }
  float mx0 = a0[0];
#pragma unroll
  for (int k = 1; k < 19; ++k) mx0 = fmaxf(mx0, a0[k]);
  float s0 = 0.f;
#pragma unroll
  for (int k = 0; k < 19; ++k) { a0[k] = __expf(a0[k] - mx0); s0 += a0[k]; }
  float r0 = 1.f / s0;
#pragma unroll
  for (int k = 0; k < 19; ++k) {
    float q0 = a0[k] * r0;
    pl[k][tid] = q0;
    a0[k] = q0;
  }
#pragma unroll
  for (int k = 0; k < 19; ++k) {
    float t = a0[k];
#pragma unroll
    for (int off = 32; off > 0; off >>= 1) t += __shfl_down(t, off);
    if ((tid & 63) == 0) atomicAdd(&psum[b * 19 + k], t);
  }
  __syncthreads();

  int c0 = tid * 2;
  const __hip_bfloat16* x0 = Xb + ((size_t)c0 << 14) + n0;
  const __hip_bfloat16* x1 = x0 + 16384;
  float b0[19], b1[19];
#pragma unroll
  for (int k = 0; k < 19; ++k) { b0[k] = 0.f; b1[k] = 0.f; }
  for (int nl = 0; nl < 256; ++nl) {
    float xv0 = BF2F(x0[nl]), xv1 = BF2F(x1[nl]);
#pragma unroll
    for (int kk = 0; kk < 19; ++kk) {
      float p = pl[kk][nl];
      b0[kk] = fmaf(p, xv0, b0[kk]);
      b1[kk] = fmaf(p, xv1, b1[kk]);
    }
  }
#pragma unroll
  for (int kk = 0; kk < 19; ++kk) {
    atomicAdd(&ctx[((b * 19 + kk) << 9) + c0], b0[kk]);
    atomicAdd(&ctx[((b * 19 + kk) << 9) + c0 + 1], b1[kk]);
  }
}

// ---- K5: K = k_w@(ctx/psum)+k_b ; v = v_w@(ctx/psum)+v_b ; fcls = cls_w@out_w ----
__global__ __launch_bounds__(256) void small_a_kernel(
    const float* __restrict__ ctx, const float* __restrict__ psum,
    const float* __restrict__ k_w, const float* __restrict__ k_b,
    const float* __restrict__ v_w, const float* __restrict__ v_b,
    const float* __restrict__ cls_w, const float* __restrict__ out_w,
    float* __restrict__ Kmat, float* __restrict__ vmat, float* __restrict__ fcls) {
  int i = blockIdx.x * 256 + threadIdx.x;
  if (i < 38912) {
    int half = i / 19456;
    int j = i - half * 19456;
    int d = j & 255;
    int t = j >> 8;
    const float* w = (half ? v_w : k_w) + d * 512;
    const float* cr = ctx + (t << 9);
    float s = 0.f;
    for (int c = 0; c < 512; ++c) s = fmaf(w[c], cr[c], s);
    float rcp = 1.f / fmaxf(psum[t], 1e-6f);
    float bias = (half ? v_b : k_b)[d];
    (half ? vmat : Kmat)[j] = s * rcp + bias;
  } else if (i < 43776) {
    int j = i - 38912;
    int vv = j & 255, k = j >> 8;
    const float* cw = cls_w + k * 512;
    float s = 0.f;
    for (int c = 0; c < 512; ++c) s = fmaf(cw[c], out_w[c * 256 + vv], s);
    fcls[j] = s;
  }
}

// ---- K6: m_t and g ----
__global__ __launch_bounds__(256) void small_b_kernel(
    const float* __restrict__ Kmat, const float* __restrict__ vmat,
    const float* __restrict__ fcls, const float* __restrict__ q_w,
    float* __restrict__ m_t, float* __restrict__ g) {
  int i = blockIdx.x * 256 + threadIdx.x;
  if (i < 38912) {
    int kk = i % 19;
    int t = i / 19;
    int c = t & 511, b = t >> 9;
    const float* kr = Kmat + ((b * 19 + kk) << 8);
    float s = 0.f;
    for (int d = 0; d < 256; ++d) s = fmaf(q_w[d * 512 + c], kr[d], s);
    m_t[i] = s;
  } else if (i < 40356) {
    int j = i - 38912;
    int k = j % 19;
    int t = j / 19;
    const float* vr = vmat + (t << 8);
    const float* fr = fcls + (k << 8);
    float s = 0.f;
    for (int v = 0; v < 256; ++v) s = fmaf(fr[v], vr[v], s);
    g[j] = s;
  }
}

// ---- K7: fused attn-softmax + final logits (writes logits half only) ----
__global__ __launch_bounds__(256) void final_fused_kernel(
    const __hip_bfloat16* __restrict__ X, const float* __restrict__ m_t,
    const float* __restrict__ cls_wt, const float* __restrict__ cls_b,
    const float* __restrict__ g, float* __restrict__ out) {
  int b = blockIdx.y;
  int n = blockIdx.x * 256 + threadIdx.x;
  float macc[19], cacc[19];
#pragma unroll
  for (int k = 0; k < 19; ++k) { macc[k] = 0.f; cacc[k] = 0.f; }
  const __hip_bfloat16* xp = X + (((size_t)b * 512) << 14) + n;
  for (int c = 0; c < 512; ++c) {
    float xv = BF2F(xp[(size_t)c << 14]);
    const float* mr = m_t + (b * 512 + c) * 19;
    const float* wr = cls_wt + c * 19;
#pragma unroll
    for (int k = 0; k < 19; ++k) {
      macc[k] = fmaf(mr[k], xv, macc[k]);
      cacc[k] = fmaf(wr[k], xv, cacc[k]);
    }
  }
  float mx = -1e30f;
#pragma unroll
  for (int k = 0; k < 19; ++k) { macc[k] *= 0.0625f; mx = fmaxf(mx, macc[k]); }
  float sum = 0.f;
#pragma unroll
  for (int k = 0; k < 19; ++k) { macc[k] = __expf(macc[k] - mx); sum += macc[k]; }
  float r = 1.f / sum;
#pragma unroll
  for (int k = 0; k < 19; ++k) cacc[k] += cls_b[k];
#pragma unroll
  for (int kk = 0; kk < 19; ++kk) {
    float av = macc[kk] * r;
    const float* gr = g + (b * 19 + kk) * 19;
#pragma unroll
    for (int k = 0; k < 19; ++k) cacc[k] = fmaf(gr[k], av, cacc[k]);
  }
  size_t ob = ((size_t)b * 19) << 14;
#pragma unroll
  for (int k = 0; k < 19; ++k)
    out[ob + ((size_t)k << 14) + n] = scrub(cacc[k]);
}

// ---- K8 (LAST): recompute aux logits f32, overwriting aux-half scratch ----
__global__ __launch_bounds__(256) void aux_final_kernel(
    const __hip_bfloat16* __restrict__ X, const float* __restrict__ aux_w,
    const float* __restrict__ aux_b, float* __restrict__ aux_out) {
  __shared__ float wt[9728];
  for (int i = threadIdx.x; i < 9728; i += 256) {
    int k = i >> 9, c = i & 511;
    wt[c * 19 + k] = aux_w[i];
  }
  __syncthreads();
  int b = blockIdx.y;
  int n = blockIdx.x * 256 + threadIdx.x;
  float acc[19];
#pragma unroll
  for (int k = 0; k < 19; ++k) acc[k] = aux_b[k];
  const __hip_bfloat16* xp = X + (((size_t)b * 512) << 14) + n;
  for (int c = 0; c < 512; ++c) {
    float xv = BF2F(xp[(size_t)c << 14]);
    const float* wr = &wt[c * 19];
#pragma unroll
    for (int k = 0; k < 19; ++k) acc[k] = fmaf(wr[k], xv, acc[k]);
  }
  size_t ob = ((size_t)b * 19) << 14;
#pragma unroll
  for (int k = 0; k < 19; ++k)
    aux_out[ob + ((size_t)k << 14) + n] = scrub(acc[k]);
}

extern "C" void kernel_launch(void* const* d_in, const int* in_sizes, int n_in,
                              void* d_out, int out_size, void* d_ws, size_t ws_size,
                              hipStream_t stream) {
  const float* feats = (const float*)d_in[0];
  const float* w3    = (const float*)d_in[1];
  const float* gamma = (const float*)d_in[2];
  const float* beta  = (const float*)d_in[3];
  const float* aux_w = (const float*)d_in[4];
  const float* aux_b = (const float*)d_in[5];
  const float* q_w   = (const float*)d_in[6];
  const float* k_w   = (const float*)d_in[7];
  const float* k_b   = (const float*)d_in[8];
  const float* v_w   = (const float*)d_in[9];
  const float* v_b   = (const float*)d_in[10];
  const float* out_w = (const float*)d_in[11];
  const float* cls_w = (const float*)d_in[12];
  const float* cls_b = (const float*)d_in[13];

  float* logits_out = (float*)d_out;
  float* aux_out    = logits_out + 1245184;

  __hip_bfloat16* X = (__hip_bfloat16*)d_ws;  // 64 MiB

  char* ob = (char*)d_out;
  __hip_bfloat16* Apack = (__hip_bfloat16*)(ob + SO_APACK);
  float* aux_wt = (float*)(ob + TA_AUXWT);
  float* cls_wt = (float*)(ob + TA_CLSWT);
  float* ssbuf  = (float*)(ob + TA_SS);
  float* psum   = (float*)(ob + TA_PSUM);
  float* ctx    = (float*)(ob + TA_CTX);
  float* Kmat   = (float*)(ob + TA_KMAT);
  float* vmat   = (float*)(ob + TA_VMAT);
  float* fcls   = (float*)(ob + TA_FCLS);
  float* m_t    = (float*)(ob + TA_MT);
  float* g      = (float*)(ob + TA_G);

  hipMemsetAsync(ob + TA_PSUM, 0, 512 + 155648, stream);

  prep_small_kernel<<<38, 256, 0, stream>>>(aux_w, cls_w, aux_wt, cls_wt);
  prep_apack_kernel<<<1472, 256, 0, stream>>>(w3, Apack);
  conv_mfma_kernel<<<1024, 256, 0, stream>>>(feats, Apack, X);
  bn_stats_kernel<<<512, 256, 0, stream>>>(X, gamma, beta, ssbuf);
  bn_apply_kernel<<<16384, 256, 0, stream>>>(X, ssbuf);
  aux_ctx_kernel<<<dim3(64, 4), 256, 0, stream>>>(X, aux_wt, aux_b, ctx, psum);
  small_a_kernel<<<171, 256, 0, stream>>>(ctx, psum, k_w, k_b, v_w, v_b, cls_w, out_w,
                                          Kmat, vmat, fcls);
  small_b_kernel<<<158, 256, 0, stream>>>(Kmat, vmat, fcls, q_w, m_t, g);
  final_fused_kernel<<<dim3(64, 4), 256, 0, stream>>>(X, m_t, cls_wt, cls_b, g, logits_out);
  aux_final_kernel<<<dim3(64, 4), 256, 0, stream>>>(X, aux_w, aux_b, aux_out);
}

// Round 5
// 1364.335 us; speedup vs baseline: 1.2022x; 1.2022x over previous
//
#include <hip/hip_runtime.h>
#include <hip/hip_bf16.h>

// OCRHead: B=4, CIN=720, H=W=128, MID=512, KC=VC=256, NC=19.
// Inputs/outputs: float32. d_out = logits[1245184] ++ aux_logits[1245184] (f32)
//
// Conv3x3 as MFMA implicit GEMM (round-3 structure: 128 oc x 128 px blocks,
// ~2.6 blocks/CU for inter-block overlap -- round-4's 2-row tile collapsed
// occupancy to 1 block/CU and regressed 28%).
//
// v5 = round-3 + T14 async-stage split: next K-block's 24 float2 feats loads
// are issued into registers right after the stage-visible barrier, hiding
// global latency under the 144-MFMA phase; only cvt+ds_write remain between
// barriers. pre[3][8] is statically indexed (full unroll) to stay in VGPRs.
//
// LDS [w'=130][r=3][ci pad 40] bf16 (halo cols w'=0,129 zeroed).
//   writes: 2x ds_write_b128/lane; lane word-stride 120==24 mod 32 -> 2-way
//   conflict (free). reads: b128 frags, 8 words/bank = wave minimum.
// Staging loads: wave w owns ci slice w*8..+7, lane owns col pair -> each
// load instruction is one fully-contiguous 512B row.
//
// Grid swizzle: bid=((gx>>3)*4+oc_t)*8+(gx&7): 4 oc_t sharers of one gx land
// adjacent on one XCD (FETCH dropped 2.9x when introduced).
//
// d_ws: X bf16 only (64 MiB). Apack + small f32 scratch live inside d_out:
//   Apack at d_out[0..6.78MB)  (consumed by conv; logits half overwritten later)
//   small scratch at tail of aux half (overwritten by aux_final, which runs last)

__device__ __forceinline__ float u_lo(unsigned u) { return __uint_as_float(u << 16); }
__device__ __forceinline__ float u_hi(unsigned u) { return __uint_as_float(u & 0xffff0000u); }
__device__ __forceinline__ float scrub(float v) { return isfinite(v) ? v : 1e4f; }
#define BF2F(h) __bfloat162float(h)

typedef __attribute__((ext_vector_type(8))) short bf16x8;
typedef __attribute__((ext_vector_type(4))) float f32x4;

// ---- d_out scratch offsets (bytes). d_out total = 9,961,472 B ----
#define SO_APACK  0ull            // 9*512*736*2 = 6,782,976
#define TAIL0     9371648ull      // = 9,961,472 - 589,824
#define TA_AUXWT  (TAIL0 + 0ull)       // 38,912
#define TA_CLSWT  (TAIL0 + 38912ull)   // 38,912
#define TA_SS     (TAIL0 + 77824ull)   // 4,096
#define TA_PSUM   (TAIL0 + 81920ull)   // 512    (memset 0)
#define TA_CTX    (TAIL0 + 82432ull)   // 155,648 (memset 0)
#define TA_KMAT   (TAIL0 + 238080ull)  // 77,824
#define TA_VMAT   (TAIL0 + 315904ull)  // 77,824
#define TA_FCLS   (TAIL0 + 393728ull)  // 19,456
#define TA_MT     (TAIL0 + 413184ull)  // 155,648
#define TA_G      (TAIL0 + 568832ull)  // 5,776  ; end 574,608 < 589,824

// LDS B-tile geometry (elements)
#define LDS_CI   40              // padded ci stride (16B-aligned frag reads)
#define LDS_ROW  (3 * LDS_CI)    // 120 per w' column
#define LDS_TOT  (130 * LDS_ROW) // 15,600 elements = 31,200 B

// ---- K0: transpose 19x512 weights to [512][19] f32 ----
__global__ __launch_bounds__(256) void prep_small_kernel(
    const float* __restrict__ aux_w, const float* __restrict__ cls_w,
    float* __restrict__ aux_wt, float* __restrict__ cls_wt) {
  int i = blockIdx.x * 256 + threadIdx.x;
  if (i < 9728) {
    int k = i >> 9, c = i & 511;
    aux_wt[c * 19 + k] = aux_w[i];
    cls_wt[c * 19 + k] = cls_w[i];
  }
}

// ---- K0b: pack conv weights f32 [512][720][3][3] -> bf16 Apack[9][512][736] ----
__global__ __launch_bounds__(256) void prep_apack_kernel(
    const float* __restrict__ w3, __hip_bfloat16* __restrict__ Apack) {
  int idx = blockIdx.x * 256 + threadIdx.x;
  if (idx >= 512 * 736) return;
  int oc = idx / 736, ci = idx - (idx / 736) * 736;
  float v[9];
#pragma unroll
  for (int k = 0; k < 9; ++k) v[k] = 0.f;
  if (ci < 720) {
    const float* src = w3 + ((size_t)oc * 720 + ci) * 9;
#pragma unroll
    for (int k = 0; k < 9; ++k) v[k] = src[k];
  }
#pragma unroll
  for (int k = 0; k < 9; ++k)
    Apack[((size_t)k * 512 + oc) * 736 + ci] = __float2bfloat16(v[k]);
}

// ---- K1: conv3x3 via MFMA implicit GEMM. Block: 128 oc x 128 px (one row) ----
__global__ __launch_bounds__(256) void conv_mfma_kernel(
    const float* __restrict__ feats, const __hip_bfloat16* __restrict__ Apack,
    __hip_bfloat16* __restrict__ X) {
  __shared__ short Blds[LDS_TOT];
  // XCD-aware decode: bid = ((gx>>3)*4 + oc_t)*8 + (gx&7); xcd = bid&7.
  int bid = blockIdx.x;
  int xcd = bid & 7;
  int slot = bid >> 3;              // 0..255
  int oc_t = slot & 3;              // 0..3
  int gx = (slot >> 2) * 8 + xcd;   // 0..511 = b*128 + h
  int b = gx >> 7, h = gx & 127;
  int tid = threadIdx.x;
  int wave = tid >> 6, lane = tid & 63;
  int wm = wave >> 1, wn = wave & 1;
  int l15 = lane & 15, quad = lane >> 4;

  f32x4 acc[4][4];
#pragma unroll
  for (int mb = 0; mb < 4; ++mb)
#pragma unroll
    for (int nb = 0; nb < 4; ++nb) acc[mb][nb] = (f32x4){0.f, 0.f, 0.f, 0.f};

  // zero halo columns w'=0 and w'=129 (never overwritten afterwards)
  for (int i = tid; i < 2 * LDS_ROW; i += 256) {
    int wp = (i < LDS_ROW) ? 0 : 129;
    Blds[wp * LDS_ROW + (i < LDS_ROW ? i : i - LDS_ROW)] = 0;
  }

  const short* Ab = (const short*)Apack;
  int oc_row = oc_t * 128 + wm * 64 + l15;

  // staging: wave owns ci slice wave*8..+7 of each K-block; lane owns col pair
  const float* fbase = feats + (((size_t)b * 720) << 14) + lane * 2;

  // T14 prefetch registers: iteration cb+1's feats (3 rows x 8 ci) live
  // across the MFMA phase. Fully static indexing (rule #20).
  float2 pre[3][8];
  {
    int ci0 = wave * 8;  // cb = 0; always < 720
#pragma unroll
    for (int r = 0; r < 3; ++r) {
      int hr = h - 1 + r;
#pragma unroll
      for (int j = 0; j < 8; ++j) pre[r][j] = (float2){0.f, 0.f};
      if ((unsigned)hr < 128u) {
        const float* p = fbase + ((size_t)ci0 << 14) + hr * 128;
#pragma unroll
        for (int j = 0; j < 8; ++j)
          pre[r][j] = *reinterpret_cast<const float2*>(p + (size_t)j * 16384);
      }
    }
  }

  for (int cb = 0; cb < 23; ++cb) {
    __syncthreads();  // previous iteration's LDS reads done before overwrite
    // ---- stage pre -> LDS (cvt + 2x ds_write_b128 per r) ----
#pragma unroll
    for (int r = 0; r < 3; ++r) {
      union { bf16x8 v; __hip_bfloat16 hh[8]; } E, O;
#pragma unroll
      for (int j = 0; j < 8; ++j) {
        E.hh[j] = __float2bfloat16(pre[r][j].x);
        O.hh[j] = __float2bfloat16(pre[r][j].y);
      }
      short* wb = &Blds[(lane * 2 + 1) * LDS_ROW + r * LDS_CI + wave * 8];
      *reinterpret_cast<bf16x8*>(wb) = E.v;
      *reinterpret_cast<bf16x8*>(wb + LDS_ROW) = O.v;
    }
    __syncthreads();
    // ---- prefetch cb+1 into regs; loads fly under the MFMA phase ----
    if (cb < 22) {
      int ci0 = (cb + 1) * 32 + wave * 8;
      bool civ = (ci0 < 720);
#pragma unroll
      for (int r = 0; r < 3; ++r) {
        int hr = h - 1 + r;
#pragma unroll
        for (int j = 0; j < 8; ++j) pre[r][j] = (float2){0.f, 0.f};
        if (civ && ((unsigned)hr < 128u)) {
          const float* p = fbase + ((size_t)ci0 << 14) + hr * 128;
#pragma unroll
          for (int j = 0; j < 8; ++j)
            pre[r][j] = *reinterpret_cast<const float2*>(p + (size_t)j * 16384);
        }
      }
    }
    // ---- 9 shift-GEMM K-steps (K=32 each) ----
#pragma unroll
    for (int r = 0; r < 3; ++r) {
#pragma unroll
      for (int dw = 0; dw < 3; ++dw) {
        int plane = r * 3 + dw;
        const short* ap = Ab + ((size_t)plane * 512 + oc_row) * 736 + cb * 32 + quad * 8;
        bf16x8 af[4];
#pragma unroll
        for (int mb = 0; mb < 4; ++mb)
          af[mb] = *(const bf16x8*)(ap + (size_t)mb * 16 * 736);
        bf16x8 bfr[4];
#pragma unroll
        for (int nb = 0; nb < 4; ++nb) {
          int px = wn * 64 + nb * 16 + l15;
          bfr[nb] = *(const bf16x8*)(&Blds[(px + dw) * LDS_ROW + r * LDS_CI + quad * 8]);
        }
#pragma unroll
        for (int mb = 0; mb < 4; ++mb)
#pragma unroll
          for (int nb = 0; nb < 4; ++nb)
            acc[mb][nb] = __builtin_amdgcn_mfma_f32_16x16x32_bf16(
                af[mb], bfr[nb], acc[mb][nb], 0, 0, 0);
      }
    }
  }
  // ---- epilogue: D row = (quad*4+reg) within 16-oc block, col = l15 px ----
#pragma unroll
  for (int mb = 0; mb < 4; ++mb)
#pragma unroll
    for (int nb = 0; nb < 4; ++nb) {
      int px = wn * 64 + nb * 16 + l15;
#pragma unroll
      for (int reg = 0; reg < 4; ++reg) {
        int oc = oc_t * 128 + wm * 64 + mb * 16 + quad * 4 + reg;
        X[(((size_t)b * 512 + oc) << 14) + h * 128 + px] =
            __float2bfloat16(acc[mb][nb][reg]);
      }
    }
}

// ---- K2: per-channel BN stats -> scale/shift ----
__global__ __launch_bounds__(256) void bn_stats_kernel(
    const __hip_bfloat16* __restrict__ X, const float* __restrict__ gamma,
    const float* __restrict__ beta, float* __restrict__ ss_out) {
  int c = blockIdx.x, tid = threadIdx.x;
  float s = 0.f, ss = 0.f;
  for (int b = 0; b < 4; ++b) {
    const __hip_bfloat16* p = X + (((size_t)b * 512 + c) << 14);
    for (int n = tid * 8; n < 16384; n += 2048) {
      uint4 u = *reinterpret_cast<const uint4*>(p + n);
      unsigned arr[4] = {u.x, u.y, u.z, u.w};
#pragma unroll
      for (int j = 0; j < 4; ++j) {
        float f0 = u_lo(arr[j]), f1 = u_hi(arr[j]);
        s += f0 + f1;
        ss += f0 * f0 + f1 * f1;
      }
    }
  }
#pragma unroll
  for (int off = 32; off > 0; off >>= 1) {
    s += __shfl_down(s, off);
    ss += __shfl_down(ss, off);
  }
  __shared__ float red[8];
  int wid = tid >> 6, lane = tid & 63;
  if (lane == 0) { red[wid] = s; red[4 + wid] = ss; }
  __syncthreads();
  if (tid == 0) {
    s = red[0] + red[1] + red[2] + red[3];
    ss = red[4] + red[5] + red[6] + red[7];
    float mean = s * (1.f / 65536.f);
    float var = ss * (1.f / 65536.f) - mean * mean;
    float gi = gamma[c] * rsqrtf(var + 1e-5f);
    ss_out[c * 2] = gi;
    ss_out[c * 2 + 1] = beta[c] - mean * gi;
  }
}

// ---- K3: x = relu(y*scale+shift) in place (bf16) ----
__global__ __launch_bounds__(256) void bn_apply_kernel(
    __hip_bfloat16* __restrict__ X, const float* __restrict__ ss) {
  size_t idx = ((size_t)blockIdx.x * 256 + threadIdx.x) * 8;
  int c = (int)((idx >> 14) & 511);
  float sc = ss[c * 2], sh = ss[c * 2 + 1];
  uint4 u = *reinterpret_cast<const uint4*>(X + idx);
  unsigned arr[4] = {u.x, u.y, u.z, u.w};
  union { uint4 u; __hip_bfloat16 h[8]; } O;
#pragma unroll
  for (int j = 0; j < 4; ++j) {
    float f0 = fmaxf(fmaf(u_lo(arr[j]), sc, sh), 0.f);
    float f1 = fmaxf(fmaf(u_hi(arr[j]), sc, sh), 0.f);
    O.h[2 * j] = __float2bfloat16(f0);
    O.h[2 * j + 1] = __float2bfloat16(f1);
  }
  *reinterpret_cast<uint4*>(X + idx) = O.u;
}

// ---- K4: aux logits (regs) -> softmax -> ctx/psum accumulation ----
__global__ __launch_bounds__(256) void aux_ctx_kernel(
    const __hip_bfloat16* __restrict__ X, const float* __restrict__ aux_wt,
    const float* __restrict__ aux_b,
    float* __restrict__ ctx, float* __restrict__ psum) {
  int b = blockIdx.y;
  int n0 = blockIdx.x * 256;
  int tid = threadIdx.x;
  __shared__ float pl[19][256];

  const __hip_bfloat16* Xb = X + (((size_t)b * 512) << 14);

  int p0 = n0 + tid;
  float a0[19];
#pragma unroll
  for (int k = 0; k < 19; ++k) a0[k] = aux_b[k];
  for (int c = 0; c < 512; ++c) {
    float f0 = BF2F(Xb[((size_t)c << 14) + p0]);
    const float* wr = aux_wt + c * 19;
#pragma unroll
    for (int k = 0; k < 19; ++k) a0[k] = fmaf(wr[k], f0, a0[k]);
  }
  float mx0 = a0[0];
#pragma unroll
  for (int k = 1; k < 19; ++k) mx0 = fmaxf(mx0, a0[k]);
  float s0 = 0.f;
#pragma unroll
  for (int k = 0; k < 19; ++k) { a0[k] = __expf(a0[k] - mx0); s0 += a0[k]; }
  float r0 = 1.f / s0;
#pragma unroll
  for (int k = 0; k < 19; ++k) {
    float q0 = a0[k] * r0;
    pl[k][tid] = q0;
    a0[k] = q0;
  }
#pragma unroll
  for (int k = 0; k < 19; ++k) {
    float t = a0[k];
#pragma unroll
    for (int off = 32; off > 0; off >>= 1) t += __shfl_down(t, off);
    if ((tid & 63) == 0) atomicAdd(&psum[b * 19 + k], t);
  }
  __syncthreads();

  int c0 = tid * 2;
  const __hip_bfloat16* x0 = Xb + ((size_t)c0 << 14) + n0;
  const __hip_bfloat16* x1 = x0 + 16384;
  float b0[19], b1[19];
#pragma unroll
  for (int k = 0; k < 19; ++k) { b0[k] = 0.f; b1[k] = 0.f; }
  for (int nl = 0; nl < 256; ++nl) {
    float xv0 = BF2F(x0[nl]), xv1 = BF2F(x1[nl]);
#pragma unroll
    for (int kk = 0; kk < 19; ++kk) {
      float p = pl[kk][nl];
      b0[kk] = fmaf(p, xv0, b0[kk]);
      b1[kk] = fmaf(p, xv1, b1[kk]);
    }
  }
#pragma unroll
  for (int kk = 0; kk < 19; ++kk) {
    atomicAdd(&ctx[((b * 19 + kk) << 9) + c0], b0[kk]);
    atomicAdd(&ctx[((b * 19 + kk) << 9) + c0 + 1], b1[kk]);
  }
}

// ---- K5: K = k_w@(ctx/psum)+k_b ; v = v_w@(ctx/psum)+v_b ; fcls = cls_w@out_w ----
__global__ __launch_bounds__(256) void small_a_kernel(
    const float* __restrict__ ctx, const float* __restrict__ psum,
    const float* __restrict__ k_w, const float* __restrict__ k_b,
    const float* __restrict__ v_w, const float* __restrict__ v_b,
    const float* __restrict__ cls_w, const float* __restrict__ out_w,
    float* __restrict__ Kmat, float* __restrict__ vmat, float* __restrict__ fcls) {
  int i = blockIdx.x * 256 + threadIdx.x;
  if (i < 38912) {
    int half = i / 19456;
    int j = i - half * 19456;
    int d = j & 255;
    int t = j >> 8;
    const float* w = (half ? v_w : k_w) + d * 512;
    const float* cr = ctx + (t << 9);
    float s = 0.f;
    for (int c = 0; c < 512; ++c) s = fmaf(w[c], cr[c], s);
    float rcp = 1.f / fmaxf(psum[t], 1e-6f);
    float bias = (half ? v_b : k_b)[d];
    (half ? vmat : Kmat)[j] = s * rcp + bias;
  } else if (i < 43776) {
    int j = i - 38912;
    int vv = j & 255, k = j >> 8;
    const float* cw = cls_w + k * 512;
    float s = 0.f;
    for (int c = 0; c < 512; ++c) s = fmaf(cw[c], out_w[c * 256 + vv], s);
    fcls[j] = s;
  }
}

// ---- K6: m_t and g ----
__global__ __launch_bounds__(256) void small_b_kernel(
    const float* __restrict__ Kmat, const float* __restrict__ vmat,
    const float* __restrict__ fcls, const float* __restrict__ q_w,
    float* __restrict__ m_t, float* __restrict__ g) {
  int i = blockIdx.x * 256 + threadIdx.x;
  if (i < 38912) {
    int kk = i % 19;
    int t = i / 19;
    int c = t & 511, b = t >> 9;
    const float* kr = Kmat + ((b * 19 + kk) << 8);
    float s = 0.f;
    for (int d = 0; d < 256; ++d) s = fmaf(q_w[d * 512 + c], kr[d], s);
    m_t[i] = s;
  } else if (i < 40356) {
    int j = i - 38912;
    int k = j % 19;
    int t = j / 19;
    const float* vr = vmat + (t << 8);
    const float* fr = fcls + (k << 8);
    float s = 0.f;
    for (int v = 0; v < 256; ++v) s = fmaf(fr[v], vr[v], s);
    g[j] = s;
  }
}

// ---- K7: fused attn-softmax + final logits (writes logits half only) ----
__global__ __launch_bounds__(256) void final_fused_kernel(
    const __hip_bfloat16* __restrict__ X, const float* __restrict__ m_t,
    const float* __restrict__ cls_wt, const float* __restrict__ cls_b,
    const float* __restrict__ g, float* __restrict__ out) {
  int b = blockIdx.y;
  int n = blockIdx.x * 256 + threadIdx.x;
  float macc[19], cacc[19];
#pragma unroll
  for (int k = 0; k < 19; ++k) { macc[k] = 0.f; cacc[k] = 0.f; }
  const __hip_bfloat16* xp = X + (((size_t)b * 512) << 14) + n;
  for (int c = 0; c < 512; ++c) {
    float xv = BF2F(xp[(size_t)c << 14]);
    const float* mr = m_t + (b * 512 + c) * 19;
    const float* wr = cls_wt + c * 19;
#pragma unroll
    for (int k = 0; k < 19; ++k) {
      macc[k] = fmaf(mr[k], xv, macc[k]);
      cacc[k] = fmaf(wr[k], xv, cacc[k]);
    }
  }
  float mx = -1e30f;
#pragma unroll
  for (int k = 0; k < 19; ++k) { macc[k] *= 0.0625f; mx = fmaxf(mx, macc[k]); }
  float sum = 0.f;
#pragma unroll
  for (int k = 0; k < 19; ++k) { macc[k] = __expf(macc[k] - mx); sum += macc[k]; }
  float r = 1.f / sum;
#pragma unroll
  for (int k = 0; k < 19; ++k) cacc[k] += cls_b[k];
#pragma unroll
  for (int kk = 0; kk < 19; ++kk) {
    float av = macc[kk] * r;
    const float* gr = g + (b * 19 + kk) * 19;
#pragma unroll
    for (int k = 0; k < 19; ++k) cacc[k] = fmaf(gr[k], av, cacc[k]);
  }
  size_t ob = ((size_t)b * 19) << 14;
#pragma unroll
  for (int k = 0; k < 19; ++k)
    out[ob + ((size_t)k << 14) + n] = scrub(cacc[k]);
}

// ---- K8 (LAST): recompute aux logits f32, overwriting aux-half scratch ----
__global__ __launch_bounds__(256) void aux_final_kernel(
    const __hip_bfloat16* __restrict__ X, const float* __restrict__ aux_w,
    const float* __restrict__ aux_b, float* __restrict__ aux_out) {
  __shared__ float wt[9728];
  for (int i = threadIdx.x; i < 9728; i += 256) {
    int k = i >> 9, c = i & 511;
    wt[c * 19 + k] = aux_w[i];
  }
  __syncthreads();
  int b = blockIdx.y;
  int n = blockIdx.x * 256 + threadIdx.x;
  float acc[19];
#pragma unroll
  for (int k = 0; k < 19; ++k) acc[k] = aux_b[k];
  const __hip_bfloat16* xp = X + (((size_t)b * 512) << 14) + n;
  for (int c = 0; c < 512; ++c) {
    float xv = BF2F(xp[(size_t)c << 14]);
    const float* wr = &wt[c * 19];
#pragma unroll
    for (int k = 0; k < 19; ++k) acc[k] = fmaf(wr[k], xv, acc[k]);
  }
  size_t ob = ((size_t)b * 19) << 14;
#pragma unroll
  for (int k = 0; k < 19; ++k)
    aux_out[ob + ((size_t)k << 14) + n] = scrub(acc[k]);
}

extern "C" void kernel_launch(void* const* d_in, const int* in_sizes, int n_in,
                              void* d_out, int out_size, void* d_ws, size_t ws_size,
                              hipStream_t stream) {
  const float* feats = (const float*)d_in[0];
  const float* w3    = (const float*)d_in[1];
  const float* gamma = (const float*)d_in[2];
  const float* beta  = (const float*)d_in[3];
  const float* aux_w = (const float*)d_in[4];
  const float* aux_b = (const float*)d_in[5];
  const float* q_w   = (const float*)d_in[6];
  const float* k_w   = (const float*)d_in[7];
  const float* k_b   = (const float*)d_in[8];
  const float* v_w   = (const float*)d_in[9];
  const float* v_b   = (const float*)d_in[10];
  const float* out_w = (const float*)d_in[11];
  const float* cls_w = (const float*)d_in[12];
  const float* cls_b = (const float*)d_in[13];

  float* logits_out = (float*)d_out;
  float* aux_out    = logits_out + 1245184;

  __hip_bfloat16* X = (__hip_bfloat16*)d_ws;  // 64 MiB

  char* ob = (char*)d_out;
  __hip_bfloat16* Apack = (__hip_bfloat16*)(ob + SO_APACK);
  float* aux_wt = (float*)(ob + TA_AUXWT);
  float* cls_wt = (float*)(ob + TA_CLSWT);
  float* ssbuf  = (float*)(ob + TA_SS);
  float* psum   = (float*)(ob + TA_PSUM);
  float* ctx    = (float*)(ob + TA_CTX);
  float* Kmat   = (float*)(ob + TA_KMAT);
  float* vmat   = (float*)(ob + TA_VMAT);
  float* fcls   = (float*)(ob + TA_FCLS);
  float* m_t    = (float*)(ob + TA_MT);
  float* g      = (float*)(ob + TA_G);

  hipMemsetAsync(ob + TA_PSUM, 0, 512 + 155648, stream);

  prep_small_kernel<<<38, 256, 0, stream>>>(aux_w, cls_w, aux_wt, cls_wt);
  prep_apack_kernel<<<1472, 256, 0, stream>>>(w3, Apack);
  conv_mfma_kernel<<<2048, 256, 0, stream>>>(feats, Apack, X);
  bn_stats_kernel<<<512, 256, 0, stream>>>(X, gamma, beta, ssbuf);
  bn_apply_kernel<<<16384, 256, 0, stream>>>(X, ssbuf);
  aux_ctx_kernel<<<dim3(64, 4), 256, 0, stream>>>(X, aux_wt, aux_b, ctx, psum);
  small_a_kernel<<<171, 256, 0, stream>>>(ctx, psum, k_w, k_b, v_w, v_b, cls_w, out_w,
                                          Kmat, vmat, fcls);
  small_b_kernel<<<158, 256, 0, stream>>>(Kmat, vmat, fcls, q_w, m_t, g);
  final_fused_kernel<<<dim3(64, 4), 256, 0, stream>>>(X, m_t, cls_wt, cls_b, g, logits_out);
  aux_final_kernel<<<dim3(64, 4), 256, 0, stream>>>(X, aux_w, aux_b, aux_out);
}